// Round 7
// baseline (826.458 us; speedup 1.0000x reference)
//
#include <hip/hip_runtime.h>
#include <hip/hip_bf16.h>

#define N_      100000
#define E_      1600000
#define G_      512
#define H_      128
#define T_      10
#define BN_EPS  1e-5f

#define NB_     782        // dst buckets of 128 nodes: ceil(100000/128)
#define NBLK_   256        // edge-chunk blocks (6250 edges each)
#define ECHUNK_ 6250
#define SCANN_  (NB_ * NBLK_)             // 200192 bucket-histogram entries
#define SCANB_  ((SCANN_ + 1023) / 1024)  // 196 scan blocks (<=256 for scan2)

typedef __attribute__((ext_vector_type(8))) short short8;
typedef __attribute__((ext_vector_type(4))) float floatx4;

__device__ __forceinline__ float bf2f(short s) {
    return __uint_as_float(((unsigned int)(unsigned short)s) << 16);
}
__device__ __forceinline__ short f2bf(float f) {
    unsigned int u = __float_as_uint(f);
    u += 0x7fffu + ((u >> 16) & 1u);          // round-to-nearest-even
    return (short)(u >> 16);
}

// ---------------------------------------------------------------------------
// convert_W: Wt[mat][n*128+k] = bf16(W[mat][k*128+n]); mats 0-3 Wa, 4-7 Wb.
// ---------------------------------------------------------------------------
__global__ __launch_bounds__(256) void convert_W(
    const float* __restrict__ Wa, const float* __restrict__ Wb,
    short* __restrict__ Wt)
{
    int i = blockIdx.x * 256 + threadIdx.x;
    if (i >= 8 * 16384) return;
    int mat = i >> 14;
    int rem = i & 16383;
    int n = rem >> 7;
    int k = rem & 127;
    const float* W = (mat < 4) ? (Wa + (size_t)mat * 16384)
                               : (Wb + (size_t)(mat - 4) * 16384);
    Wt[(size_t)mat * 16384 + n * 128 + k] = f2bf(W[k * 128 + n]);
}

// ---------------------------------------------------------------------------
// edge_hist: per-(bucket, chunk-block) histogram BH[b*NBLK_+blk] (LDS atomics).
// ---------------------------------------------------------------------------
__global__ __launch_bounds__(256) void edge_hist(const int* __restrict__ edst,
                                                 int* __restrict__ BH)
{
    __shared__ int hist[NB_];
    const int t = threadIdx.x, blk = blockIdx.x;
    for (int i = t; i < NB_; i += 256) hist[i] = 0;
    __syncthreads();
    const int base = blk * ECHUNK_;
    for (int i = base + t; i < base + ECHUNK_; i += 256)
        atomicAdd(&hist[edst[i] >> 7], 1);
    __syncthreads();
    for (int b = t; b < NB_; b += 256)
        BH[b * NBLK_ + blk] = hist[b];
}

// ---------------------------------------------------------------------------
// scan1: per-1024-chunk exclusive scan of BH -> BHs, block sums -> bsum.
// scan2: exclusive scan of bsum (single block). Consumers add bsum on the fly.
// ---------------------------------------------------------------------------
__global__ __launch_bounds__(256) void scan1(const int* __restrict__ X,
                                             int* __restrict__ Y,
                                             int* __restrict__ bsum, int n)
{
    __shared__ int sd[256];
    int t = threadIdx.x;
    int base = blockIdx.x * 1024 + t * 4;
    int c0 = (base + 0 < n) ? X[base + 0] : 0;
    int c1 = (base + 1 < n) ? X[base + 1] : 0;
    int c2 = (base + 2 < n) ? X[base + 2] : 0;
    int c3 = (base + 3 < n) ? X[base + 3] : 0;
    int s = c0 + c1 + c2 + c3;
    sd[t] = s;
    __syncthreads();
    for (int d = 1; d < 256; d <<= 1) {
        int v = (t >= d) ? sd[t - d] : 0;
        __syncthreads();
        sd[t] += v;
        __syncthreads();
    }
    int p = sd[t] - s;
    if (base + 0 < n) Y[base + 0] = p;
    if (base + 1 < n) Y[base + 1] = p + c0;
    if (base + 2 < n) Y[base + 2] = p + c0 + c1;
    if (base + 3 < n) Y[base + 3] = p + c0 + c1 + c2;
    if (t == 255) bsum[blockIdx.x] = sd[255];
}

__global__ __launch_bounds__(256) void scan2(int* __restrict__ bsum, int nb)
{
    __shared__ int sd[256];
    int t = threadIdx.x;
    int v0 = (t < nb) ? bsum[t] : 0;
    sd[t] = v0;
    __syncthreads();
    for (int d = 1; d < 256; d <<= 1) {
        int v = (t >= d) ? sd[t - d] : 0;
        __syncthreads();
        sd[t] += v;
        __syncthreads();
    }
    if (t < nb) bsum[t] = sd[t] - v0;
}

// ---------------------------------------------------------------------------
// scatter_ebuf: chunk block -> bucket-grouped ebuf (exclusive regions).
// Global offset = BHs[idx] + bsum[idx>>10].
// ---------------------------------------------------------------------------
__global__ __launch_bounds__(256) void scatter_ebuf(
    const int* __restrict__ esrc, const int* __restrict__ edst,
    const int* __restrict__ BHs, const int* __restrict__ bsum,
    int2* __restrict__ ebuf)
{
    __shared__ int sbuf[NB_];
    const int t = threadIdx.x, blk = blockIdx.x;
    for (int b = t; b < NB_; b += 256) {
        int idx = b * NBLK_ + blk;
        sbuf[b] = BHs[idx] + bsum[idx >> 10];
    }
    __syncthreads();
    const int base = blk * ECHUNK_;
    for (int i = base + t; i < base + ECHUNK_; i += 256) {
        int s = esrc[i], d = edst[i];
        int pos = atomicAdd(&sbuf[d >> 7], 1);
        ebuf[pos] = make_int2(s, d);
    }
}

// ---------------------------------------------------------------------------
// fill_buckets: bucket b -> exact CSR eidx + off[]; writes confined to the
// block's contiguous region.
// ---------------------------------------------------------------------------
__global__ __launch_bounds__(256) void fill_buckets(
    const int2* __restrict__ ebuf, const int* __restrict__ BHs,
    const int* __restrict__ bsum, int* __restrict__ eidx,
    int* __restrict__ off)
{
    __shared__ int cnt[128];
    __shared__ int sc[256];
    const int b = blockIdx.x, t = threadIdx.x;
    const int i0 = b * NBLK_;
    const int bstart = BHs[i0] + bsum[i0 >> 10];
    int bend = E_;
    if (b != NB_ - 1) {
        const int i1 = (b + 1) * NBLK_;
        bend = BHs[i1] + bsum[i1 >> 10];
    }

    if (t < 128) cnt[t] = 0;
    __syncthreads();
    for (int i = bstart + t; i < bend; i += 256)
        atomicAdd(&cnt[ebuf[i].y & 127], 1);
    __syncthreads();
    int v = (t < 128) ? cnt[t] : 0;
    sc[t] = v;
    __syncthreads();
    for (int d = 1; d < 128; d <<= 1) {
        int u = (t >= d) ? sc[t - d] : 0;
        __syncthreads();
        sc[t] += u;
        __syncthreads();
    }
    if (t < 128) {
        int node = (b << 7) + t;
        int pfx = sc[t] - v;
        if (node <= N_) off[node] = bstart + pfx;
        cnt[t] = bstart + pfx;                    // cursor
    }
    __syncthreads();
    for (int i = bstart + t; i < bend; i += 256) {
        int2 e = ebuf[i];
        int pos = atomicAdd(&cnt[e.y & 127], 1);
        eidx[pos] = e.x;
    }
}

// ---------------------------------------------------------------------------
// gemm_mfma (128-row tile): C = act(A) @ W + bias, fused BN-stats output.
// mode 1: A bf16, BN(statsIn)+ReLU fused into A-load. mode 2: A fp32.
// ---------------------------------------------------------------------------
__global__ __launch_bounds__(256) void gemm_mfma(
    const void* __restrict__ Ain, const short* __restrict__ Wt,
    const float* __restrict__ bias, short* __restrict__ Cout,
    float* __restrict__ statsOut,
    const float* __restrict__ statsIn, const float* __restrict__ gamma,
    const float* __restrict__ beta, int mode, int nrows)
{
    __shared__ __align__(16) short Bs[128][136];
    __shared__ float scale_s[128];
    __shared__ float shift_s[128];

    const int tid = threadIdx.x;

    {   // stage W^T
        int r = tid >> 1;
        int half = (tid & 1) << 6;
        const short* g = Wt + r * 128 + half;
        short* d = &Bs[r][half];
#pragma unroll
        for (int i = 0; i < 8; ++i)
            *(short8*)(d + i * 8) = *(const short8*)(g + i * 8);
    }
    if (mode == 1 && tid < 128) {
        const float nInv = 1.0f / (float)N_;
        float mu = statsIn[tid] * nInv;
        float var = statsIn[128 + tid] * nInv - mu * mu;
        float sc = gamma[tid] * rsqrtf(var + BN_EPS);
        scale_s[tid] = sc;
        shift_s[tid] = beta[tid] - mu * sc;
    }
    __syncthreads();

    const int wave = tid >> 6;
    const int lane = tid & 63;
    const int m = lane & 15;
    const int quad = lane >> 4;
    const int rowBase = blockIdx.x * 128;
    const int r0 = rowBase + wave * 32 + m;
    const int r1 = r0 + 16;
    const int a0 = r0 < nrows ? r0 : nrows - 1;
    const int a1 = r1 < nrows ? r1 : nrows - 1;

    floatx4 acc[2][8];
#pragma unroll
    for (int s = 0; s < 2; ++s)
#pragma unroll
        for (int i = 0; i < 8; ++i) acc[s][i] = (floatx4)0.f;

#pragma unroll
    for (int k0 = 0; k0 < 128; k0 += 32) {
        const int kb = k0 + quad * 8;
        short8 af[2];
        if (mode == 2) {
#pragma unroll
            for (int s = 0; s < 2; ++s) {
                const float* Af = (const float*)Ain + (size_t)(s ? a1 : a0) * 128 + kb;
                float4 x0 = *(const float4*)(Af);
                float4 x1 = *(const float4*)(Af + 4);
                af[s][0] = f2bf(x0.x); af[s][1] = f2bf(x0.y);
                af[s][2] = f2bf(x0.z); af[s][3] = f2bf(x0.w);
                af[s][4] = f2bf(x1.x); af[s][5] = f2bf(x1.y);
                af[s][6] = f2bf(x1.z); af[s][7] = f2bf(x1.w);
            }
        } else {
            af[0] = *(const short8*)((const short*)Ain + (size_t)a0 * 128 + kb);
            af[1] = *(const short8*)((const short*)Ain + (size_t)a1 * 128 + kb);
            if (mode == 1) {
                float4 sc0 = *(const float4*)&scale_s[kb];
                float4 sc1 = *(const float4*)&scale_s[kb + 4];
                float4 sh0 = *(const float4*)&shift_s[kb];
                float4 sh1 = *(const float4*)&shift_s[kb + 4];
#pragma unroll
                for (int s = 0; s < 2; ++s) {
                    af[s][0] = f2bf(fmaxf(fmaf(bf2f(af[s][0]), sc0.x, sh0.x), 0.f));
                    af[s][1] = f2bf(fmaxf(fmaf(bf2f(af[s][1]), sc0.y, sh0.y), 0.f));
                    af[s][2] = f2bf(fmaxf(fmaf(bf2f(af[s][2]), sc0.z, sh0.z), 0.f));
                    af[s][3] = f2bf(fmaxf(fmaf(bf2f(af[s][3]), sc0.w, sh0.w), 0.f));
                    af[s][4] = f2bf(fmaxf(fmaf(bf2f(af[s][4]), sc1.x, sh1.x), 0.f));
                    af[s][5] = f2bf(fmaxf(fmaf(bf2f(af[s][5]), sc1.y, sh1.y), 0.f));
                    af[s][6] = f2bf(fmaxf(fmaf(bf2f(af[s][6]), sc1.z, sh1.z), 0.f));
                    af[s][7] = f2bf(fmaxf(fmaf(bf2f(af[s][7]), sc1.w, sh1.w), 0.f));
                }
            }
        }
#pragma unroll
        for (int nt = 0; nt < 8; ++nt) {
            short8 bf = *(const short8*)&Bs[nt * 16 + m][kb];
            acc[0][nt] = __builtin_amdgcn_mfma_f32_16x16x32_bf16(af[0], bf, acc[0][nt], 0, 0, 0);
            acc[1][nt] = __builtin_amdgcn_mfma_f32_16x16x32_bf16(af[1], bf, acc[1][nt], 0, 0, 0);
        }
    }

    float (*Cs)[132] = (float(*)[132])&Bs[0][0];
    float S1 = 0.f, S2 = 0.f;
#pragma unroll
    for (int half = 0; half < 2; ++half) {
        __syncthreads();
        if ((wave >> 1) == half) {
            int wl = wave & 1;
#pragma unroll
            for (int nt = 0; nt < 8; ++nt) {
                float b = bias[nt * 16 + m];
#pragma unroll
                for (int s = 0; s < 2; ++s)
#pragma unroll
                    for (int r = 0; r < 4; ++r)
                        Cs[wl * 32 + s * 16 + quad * 4 + r][nt * 16 + m] = acc[s][nt][r] + b;
            }
        }
        __syncthreads();
        {
            int trow = tid >> 2;
            int tcg = (tid & 3) << 5;
            int grow = rowBase + half * 64 + trow;
            if (grow < nrows) {
                short* dst = Cout + (size_t)grow * 128 + tcg;
#pragma unroll
                for (int i = 0; i < 4; ++i) {
                    short8 o;
#pragma unroll
                    for (int j = 0; j < 8; ++j) o[j] = f2bf(Cs[trow][tcg + i * 8 + j]);
                    *(short8*)(dst + i * 8) = o;
                }
            }
        }
        if (tid < 128) {
            int nvalid = nrows - rowBase - half * 64;
            if (nvalid > 64) nvalid = 64;
            for (int r = 0; r < nvalid; ++r) {
                float v = Cs[r][tid];
                S1 += v; S2 += v * v;
            }
        }
    }
    if (tid < 128) {
        atomicAdd(&statsOut[tid], S1);
        atomicAdd(&statsOut[128 + tid], S2);
    }
}

// ---------------------------------------------------------------------------
// gemm_gather (64-row tile): fused GIN aggregation + GEMM.
//   A-row = (1+eps)*relu(bn(q[row])) + sum_{j in N(row)} relu(bn(q[j]))
// built in-registers per lane (32 cols = 4 chunks of 8), then MFMA with
// staged W^T.  C = A @ W + bias, bf16 out, fused BN stats.
// ---------------------------------------------------------------------------
__global__ __launch_bounds__(256) void gemm_gather(
    const short* __restrict__ Qin, const short* __restrict__ Wt,
    const float* __restrict__ bias, short* __restrict__ Cout,
    float* __restrict__ statsOut,
    const float* __restrict__ statsIn, const float* __restrict__ gamma,
    const float* __restrict__ beta, const float* __restrict__ eps, int li,
    const int* __restrict__ off, const int* __restrict__ eidx)
{
    __shared__ __align__(16) short Bs[128][136];
    __shared__ float scale_s[128];
    __shared__ float shift_s[128];

    const int tid = threadIdx.x;

    {   // stage W^T
        int r = tid >> 1;
        int half = (tid & 1) << 6;
        const short* g = Wt + r * 128 + half;
        short* d = &Bs[r][half];
#pragma unroll
        for (int i = 0; i < 8; ++i)
            *(short8*)(d + i * 8) = *(const short8*)(g + i * 8);
    }
    if (tid < 128) {   // BN consts of the PREVIOUS layer's second BN
        const float nInv = 1.0f / (float)N_;
        float mu = statsIn[tid] * nInv;
        float var = statsIn[128 + tid] * nInv - mu * mu;
        float sc = gamma[tid] * rsqrtf(var + BN_EPS);
        scale_s[tid] = sc;
        shift_s[tid] = beta[tid] - mu * sc;
    }
    __syncthreads();

    const int wave = tid >> 6;
    const int lane = tid & 63;
    const int m = lane & 15;
    const int quad = lane >> 4;
    const int rowBase = blockIdx.x * 64;
    const int row = rowBase + wave * 16 + m;
    const bool valid = row < N_;
    const int arow = valid ? row : N_ - 1;
    const int cb = quad << 3;                 // lane's base col within chunk

    // per-lane BN consts for its 32 cols
    float scv[4][8], shv[4][8];
#pragma unroll
    for (int c = 0; c < 4; ++c) {
        int col = c * 32 + cb;
        float4 s0 = *(const float4*)&scale_s[col];
        float4 s1 = *(const float4*)&scale_s[col + 4];
        float4 h0 = *(const float4*)&shift_s[col];
        float4 h1 = *(const float4*)&shift_s[col + 4];
        scv[c][0] = s0.x; scv[c][1] = s0.y; scv[c][2] = s0.z; scv[c][3] = s0.w;
        scv[c][4] = s1.x; scv[c][5] = s1.y; scv[c][6] = s1.z; scv[c][7] = s1.w;
        shv[c][0] = h0.x; shv[c][1] = h0.y; shv[c][2] = h0.z; shv[c][3] = h0.w;
        shv[c][4] = h1.x; shv[c][5] = h1.y; shv[c][6] = h1.z; shv[c][7] = h1.w;
    }

    float ga[4][8];
    const float se = 1.0f + eps[li];
    {   // self term
        const short* qr = Qin + (size_t)arow * 128 + cb;
        short8 v[4];
#pragma unroll
        for (int c = 0; c < 4; ++c) v[c] = *(const short8*)(qr + c * 32);
#pragma unroll
        for (int c = 0; c < 4; ++c)
#pragma unroll
            for (int j = 0; j < 8; ++j)
                ga[c][j] = fmaxf(fmaf(bf2f(v[c][j]), scv[c][j], shv[c][j]), 0.f) * se;
    }

    int s0e = 0, s1e = 0;
    if (valid) { s0e = off[row]; s1e = off[row + 1]; }
    for (int j = s0e; j < s1e; ++j) {
        int nb = eidx[j];
        const short* qr = Qin + (size_t)nb * 128 + cb;
        short8 v[4];
#pragma unroll
        for (int c = 0; c < 4; ++c) v[c] = *(const short8*)(qr + c * 32);
#pragma unroll
        for (int c = 0; c < 4; ++c)
#pragma unroll
            for (int jj = 0; jj < 8; ++jj)
                ga[c][jj] += fmaxf(fmaf(bf2f(v[c][jj]), scv[c][jj], shv[c][jj]), 0.f);
    }

    // convert to bf16 A-fragments
    short8 af[4];
#pragma unroll
    for (int c = 0; c < 4; ++c)
#pragma unroll
        for (int j = 0; j < 8; ++j) af[c][j] = f2bf(ga[c][j]);

    floatx4 acc[8];
#pragma unroll
    for (int i = 0; i < 8; ++i) acc[i] = (floatx4)0.f;
#pragma unroll
    for (int c = 0; c < 4; ++c) {
        const int kb = c * 32 + cb;
#pragma unroll
        for (int nt = 0; nt < 8; ++nt) {
            short8 bf = *(const short8*)&Bs[nt * 16 + m][kb];
            acc[nt] = __builtin_amdgcn_mfma_f32_16x16x32_bf16(af[c], bf, acc[nt], 0, 0, 0);
        }
    }

    // epilogue: LDS roundtrip, coalesced bf16 store, BN stats
    __syncthreads();
    float (*Cs)[132] = (float(*)[132])&Bs[0][0];   // 64*132*4 = 33792 B
#pragma unroll
    for (int nt = 0; nt < 8; ++nt) {
        float b = bias[nt * 16 + m];
#pragma unroll
        for (int r = 0; r < 4; ++r)
            Cs[wave * 16 + quad * 4 + r][nt * 16 + m] = acc[nt][r] + b;
    }
    __syncthreads();
    {
        int trow = tid >> 2;
        int tcg = (tid & 3) << 5;
        int grow = rowBase + trow;
        if (grow < N_) {
            short* dst = Cout + (size_t)grow * 128 + tcg;
#pragma unroll
            for (int i = 0; i < 4; ++i) {
                short8 o;
#pragma unroll
                for (int jj = 0; jj < 8; ++jj) o[jj] = f2bf(Cs[trow][tcg + i * 8 + jj]);
                *(short8*)(dst + i * 8) = o;
            }
        }
    }
    if (tid < 128) {
        int nvalid = N_ - rowBase;
        if (nvalid > 64) nvalid = 64;
        float S1 = 0.f, S2 = 0.f;
        for (int r = 0; r < nvalid; ++r) {
            float v = Cs[r][tid];
            S1 += v; S2 += v * v;
        }
        atomicAdd(&statsOut[tid], S1);
        atomicAdd(&statsOut[128 + tid], S2);
    }
}

// ---------------------------------------------------------------------------
// bn_pool: BN apply + ReLU + segment pool (no activation store).
// ---------------------------------------------------------------------------
__global__ __launch_bounds__(128) void bn_pool(
    const short* __restrict__ Cin, const float* __restrict__ stats,
    const float* __restrict__ gamma, const float* __restrict__ beta,
    const int* __restrict__ batch, float* __restrict__ pooled, int n)
{
    int c = threadIdx.x;
    const float nInv = 1.0f / (float)N_;
    float mu = stats[c] * nInv;
    float var = stats[128 + c] * nInv - mu * mu;
    float sc = gamma[c] * rsqrtf(var + BN_EPS);
    float sh = beta[c] - mu * sc;

    int per = (n + gridDim.x - 1) / gridDim.x;
    int r0 = blockIdx.x * per;
    int r1 = min(n, r0 + per);
    if (r0 >= r1) return;
    int curg = batch[r0];
    float s = 0.f;
    for (int r = r0; r < r1; ++r) {
        int g = batch[r];
        if (g != curg) {
            atomicAdd(&pooled[(size_t)curg * 128 + c], s);
            s = 0.f;
            curg = g;
        }
        s += fmaxf(fmaf(bf2f(Cin[(size_t)r * 128 + c]), sc, sh), 0.f);
    }
    atomicAdd(&pooled[(size_t)curg * 128 + c], s);
}

// ---------------------------------------------------------------------------
// out_final: inline per-graph count (batch sorted, binary search) + head.
// ---------------------------------------------------------------------------
__global__ void out_final(const float* __restrict__ pooled,
                          const int* __restrict__ batch,
                          const float* __restrict__ Wl,
                          const float* __restrict__ bl, float* __restrict__ out)
{
    int g = blockIdx.x;
    int t = threadIdx.x;
    if (t >= T_) return;
    int lo = 0, hi = N_;
    while (lo < hi) { int mid = (lo + hi) >> 1; if (batch[mid] < g) lo = mid + 1; else hi = mid; }
    int b0 = lo;
    lo = 0; hi = N_;
    while (lo < hi) { int mid = (lo + hi) >> 1; if (batch[mid] < g + 1) lo = mid + 1; else hi = mid; }
    float inv = 1.0f / fmaxf((float)(lo - b0), 1.0f);
    float acc = 0.f;
#pragma unroll
    for (int l = 0; l < 4; ++l) {
        float s = 0.f;
        for (int c = 0; c < 128; ++c)
            s = fmaf(pooled[(size_t)l * (G_ * H_) + g * 128 + c],
                     Wl[(size_t)l * (H_ * T_) + c * T_ + t], s);
        acc += s * inv + bl[l * T_ + t];
    }
    out[g * T_ + t] = 1.0f / (1.0f + expf(-acc));
}

// ---------------------------------------------------------------------------
extern "C" void kernel_launch(void* const* d_in, const int* in_sizes, int n_in,
                              void* d_out, int out_size, void* d_ws, size_t ws_size,
                              hipStream_t stream)
{
    const float* x    = (const float*)d_in[0];
    const int*   ei   = (const int*)d_in[1];
    const int*   batch= (const int*)d_in[2];
    const float* Wa   = (const float*)d_in[3];
    const float* ba   = (const float*)d_in[4];
    const float* ga   = (const float*)d_in[5];
    const float* bea  = (const float*)d_in[6];
    const float* Wb   = (const float*)d_in[7];
    const float* bb   = (const float*)d_in[8];
    const float* gb   = (const float*)d_in[9];
    const float* beb  = (const float*)d_in[10];
    const float* Wl   = (const float*)d_in[11];
    const float* bl   = (const float*)d_in[12];
    const float* eps  = (const float*)d_in[13];
    float* out = (float*)d_out;

    const size_t NH = (size_t)N_ * H_;
    // workspace layout
    short* A   = (short*)d_ws;                 // N x H bf16 (first-linear out)
    short* B   = A + NH;                       // N x H bf16 (q_l, pre-BN act)
    short* Wt  = B + NH;                       // 8 x 128 x 128 bf16
    float* stats  = (float*)(Wt + 8 * 16384);  // 8 x 256          [zeroed]
    float* pooled = stats + 8 * 256;           // 4 x G x 128      [zeroed]
    int*   BH     = (int*)(pooled + 4 * (size_t)G_ * H_); // SCANN_
    int*   BHs    = BH + SCANN_;               // SCANN_
    int*   bsum   = BHs + SCANN_;              // 256
    int*   off    = bsum + 256;                // 100352 (>= N_+1)
    int2*  ebuf   = (int2*)(off + 100352);     // E
    int*   eidx   = (int*)(ebuf + E_);         // E

    const size_t zbytes = (size_t)(8 * 256 + 4 * G_ * H_) * 4;
    hipMemsetAsync(stats, 0, zbytes, stream);

    const int* esrc = ei;
    const int* edst = ei + E_;

    // ---- setup: weights + CSR (bucket counting sort) ----
    convert_W<<<512, 256, 0, stream>>>(Wa, Wb, Wt);
    edge_hist<<<NBLK_, 256, 0, stream>>>(edst, BH);
    scan1<<<SCANB_, 256, 0, stream>>>(BH, BHs, bsum, SCANN_);
    scan2<<<1, 256, 0, stream>>>(bsum, SCANB_);
    scatter_ebuf<<<NBLK_, 256, 0, stream>>>(esrc, edst, BHs, bsum, ebuf);
    fill_buckets<<<NB_, 256, 0, stream>>>(ebuf, BHs, bsum, eidx, off);

    const int gemmGrid  = (N_ + 127) / 128;   // 128-row tiles
    const int ggGrid    = (N_ + 63) / 64;     // 64-row gather tiles

    // ---- layer 0 ----
    gemm_mfma<<<gemmGrid, 256, 0, stream>>>(x, Wt, ba, A, stats,
                                            nullptr, nullptr, nullptr, 2, N_);
    gemm_mfma<<<gemmGrid, 256, 0, stream>>>(A, Wt + 4 * 16384, bb, B, stats + 256,
                                            stats, ga, bea, 1, N_);
    bn_pool<<<1024, 128, 0, stream>>>(B, stats + 256, gb, beb, batch, pooled, N_);

    // ---- layers 1..3: gather-GEMM + GEMM + pool ----
    for (int l = 1; l < 4; ++l) {
        float* stA = stats + (size_t)(2 * l) * 256;
        float* stB = stats + (size_t)(2 * l + 1) * 256;
        const float* stPrev = stats + (size_t)(2 * l - 1) * 256;
        gemm_gather<<<ggGrid, 256, 0, stream>>>(B, Wt + (size_t)l * 16384,
                                                ba + l * H_, A, stA,
                                                stPrev, gb + (l - 1) * H_,
                                                beb + (l - 1) * H_, eps, l - 1,
                                                off, eidx);
        gemm_mfma<<<gemmGrid, 256, 0, stream>>>(A, Wt + (size_t)(4 + l) * 16384,
                                                bb + l * H_, B, stB,
                                                stA, ga + l * H_, bea + l * H_, 1, N_);
        bn_pool<<<1024, 128, 0, stream>>>(B, stB, gb + l * H_, beb + l * H_,
                                          batch, pooled + (size_t)l * G_ * H_, N_);
    }

    out_final<<<G_, 64, 0, stream>>>(pooled, batch, Wl, bl, out);
}